// Round 8
// baseline (163.101 us; speedup 1.0000x reference)
//
#include <hip/hip_runtime.h>
#include <math.h>

// Attention_57406532878693: T=2048,B=32,D=1024,H=8,N=128,N2=16
#define T_   2048
#define B_   32
#define D_   1024
#define H_   8
#define N_   128
#define NK   16          // N2 gate width
#define TSPL 8           // T-splits per (b,h)
#define TBLK (T_/TSPL)   // 256 t per unit
#define BD4  (B_*D_/4)
#define APS  132         // attp stride per unit (128 c + Z + pad)
#define LOG2E 1.4426950408889634f

typedef __attribute__((ext_vector_type(8))) short short8;   // bf16x8 frag
typedef __attribute__((ext_vector_type(4))) float f32x4;    // C/D frag

// split 8 fp32 (two float4) into truncated bf16 hi + bf16(lo) fragments
__device__ __forceinline__ void split_bf16(float4 a, float4 b,
                                           short8& hi, short8& lo) {
    union { uint32_t u[4]; short8 v; } H, L;
    uint32_t x0 = __float_as_uint(a.x), x1 = __float_as_uint(a.y);
    uint32_t x2 = __float_as_uint(a.z), x3 = __float_as_uint(a.w);
    uint32_t x4 = __float_as_uint(b.x), x5 = __float_as_uint(b.y);
    uint32_t x6 = __float_as_uint(b.z), x7 = __float_as_uint(b.w);
    H.u[0] = (x0 >> 16) | (x1 & 0xFFFF0000u);
    H.u[1] = (x2 >> 16) | (x3 & 0xFFFF0000u);
    H.u[2] = (x4 >> 16) | (x5 & 0xFFFF0000u);
    H.u[3] = (x6 >> 16) | (x7 & 0xFFFF0000u);
    float l0 = a.x - __uint_as_float(x0 & 0xFFFF0000u);
    float l1 = a.y - __uint_as_float(x1 & 0xFFFF0000u);
    float l2 = a.z - __uint_as_float(x2 & 0xFFFF0000u);
    float l3 = a.w - __uint_as_float(x3 & 0xFFFF0000u);
    float l4 = b.x - __uint_as_float(x4 & 0xFFFF0000u);
    float l5 = b.y - __uint_as_float(x5 & 0xFFFF0000u);
    float l6 = b.z - __uint_as_float(x6 & 0xFFFF0000u);
    float l7 = b.w - __uint_as_float(x7 & 0xFFFF0000u);
    L.u[0] = (__float_as_uint(l0) >> 16) | (__float_as_uint(l1) & 0xFFFF0000u);
    L.u[1] = (__float_as_uint(l2) >> 16) | (__float_as_uint(l3) & 0xFFFF0000u);
    L.u[2] = (__float_as_uint(l4) >> 16) | (__float_as_uint(l5) & 0xFFFF0000u);
    L.u[3] = (__float_as_uint(l6) >> 16) | (__float_as_uint(l7) & 0xFFFF0000u);
    hi = H.v; lo = L.v;
}

__device__ __forceinline__ float tanh_fast(float d) {
    return 1.f - 2.f * __frcp_rn(exp2f(d * (2.f * LOG2E)) + 1.f);
}

// load 8 float4 of x for one 16-t step (lane's t-row = t0+step*64+w*16+kk)
#define LOADX(dst, step_) { \
    const int trow_ = t0 + (step_) * 64 + w * 16 + kk; \
    const size_t rb_ = (size_t)trow_ * BD4 + base4; \
    (dst)[0] = hyp4[rb_ + g * 2];      (dst)[1] = hyp4[rb_ + g * 2 + 1]; \
    (dst)[2] = hyp4[rb_ + 8 + g * 2];  (dst)[3] = hyp4[rb_ + 8 + g * 2 + 1]; \
    (dst)[4] = hyp4[rb_ + 16 + g * 2]; (dst)[5] = hyp4[rb_ + 16 + g * 2 + 1]; \
    (dst)[6] = hyp4[rb_ + 24 + g * 2]; (dst)[7] = hyp4[rb_ + 24 + g * 2 + 1]; }

// K1: pure streaming column-sum, one block per (bh,spl) unit. Every wave
// load instruction covers 2 x 512 B contiguous rows; 4 independent
// accumulators for ILP. part[u][128].
__global__ __launch_bounds__(256, 4) void k_mean(const float4* __restrict__ hyp4,
                                                 float4* __restrict__ part4) {
    __shared__ float4 red[8 * 32];
    const int u = blockIdx.x;
    const int bh = u >> 3, spl = u & 7;
    const int b = bh >> 3, h = bh & 7;
    const int t0 = spl * TBLK;
    const int base4 = b * (D_ / 4) + h * (N_ / 4);
    const int col4 = threadIdx.x & 31;
    const int tg   = threadIdx.x >> 5;           // 8 groups x 32 t
    const size_t cbase = (size_t)(t0 + tg * 32) * BD4 + base4 + col4;

    float4 a0 = {0,0,0,0}, a1 = {0,0,0,0}, a2 = {0,0,0,0}, a3 = {0,0,0,0};
#pragma unroll
    for (int i = 0; i < 32; i += 4) {
        float4 v0 = hyp4[cbase + (size_t)(i+0) * BD4];
        float4 v1 = hyp4[cbase + (size_t)(i+1) * BD4];
        float4 v2 = hyp4[cbase + (size_t)(i+2) * BD4];
        float4 v3 = hyp4[cbase + (size_t)(i+3) * BD4];
        a0.x += v0.x; a0.y += v0.y; a0.z += v0.z; a0.w += v0.w;
        a1.x += v1.x; a1.y += v1.y; a1.z += v1.z; a1.w += v1.w;
        a2.x += v2.x; a2.y += v2.y; a2.z += v2.z; a2.w += v2.w;
        a3.x += v3.x; a3.y += v3.y; a3.z += v3.z; a3.w += v3.w;
    }
    float4 s;
    s.x = (a0.x + a1.x) + (a2.x + a3.x);
    s.y = (a0.y + a1.y) + (a2.y + a3.y);
    s.z = (a0.z + a1.z) + (a2.z + a3.z);
    s.w = (a0.w + a1.w) + (a2.w + a3.w);
    red[tg * 32 + col4] = s;
    __syncthreads();
    if (threadIdx.x < 32) {
        float4 t = {0,0,0,0};
#pragma unroll
        for (int gg = 0; gg < 8; ++gg) {
            float4 v = red[gg * 32 + threadIdx.x];
            t.x += v.x; t.y += v.y; t.z += v.z; t.w += v.w;
        }
        part4[(size_t)u * 32 + threadIdx.x] = t;
    }
}

// K2: one block per (bh,spl), reverse dispatch order (L3-MRU first).
// Prologue: mean from part + gm (k_gw folded). Hot loop: recompute gate
// dots via 3-term hi/lo bf16 MFMA (fp32-accurate), tanh, k-butterfly,
// unshifted exp (|logit|<=4), e-redistribute, weighted accumulate.
__global__ __launch_bounds__(256, 4) void k_att(const float* __restrict__ hyp,
                                                const float* __restrict__ Ww,
                                                const float* __restrict__ Wb,
                                                const float* __restrict__ part,
                                                const float* __restrict__ Wmw,
                                                const float* __restrict__ Wmb,
                                                const float* __restrict__ Whw,
                                                float* __restrict__ attp) {
    __shared__ float red[4 * N_];
    __shared__ float zred[4];
    __shared__ float m_l[N_];
    __shared__ float gw_l[NK];
    const int tid  = threadIdx.x;
    const int lane = tid & 63;
    const int w    = tid >> 6;
    const int blk  = (B_ * H_ * TSPL - 1) - (int)blockIdx.x;
    const int bh   = blk >> 3;
    const int spl  = blk & 7;
    const int b = bh >> 3, h = bh & 7;
    const int t0 = spl * TBLK;
    const float4* hyp4 = (const float4*)hyp;
    const float4* Ww4  = (const float4*)Ww;
    const int base4 = b * (D_ / 4) + h * (N_ / 4);
    const int kk = lane & 15;            // gate-k (C col) & A-row index
    const int g  = lane >> 4;            // fragment / C-row group

    // mean for this bh
    if (tid < N_) {
        float s = 0.f;
#pragma unroll
        for (int s8 = 0; s8 < TSPL; ++s8) s += part[(bh * TSPL + s8) * N_ + tid];
        m_l[tid] = s * (1.f / (float)T_);
    }
    __syncthreads();
    // gm: gw_l[k] = tanh(m.Wmw_k + Wmb_k) * Whw_k
    if (tid < N_) {
        int k = tid >> 3, g3 = tid & 7;
        float dsum = 0.f;
#pragma unroll
        for (int i = 0; i < 16; ++i) {
            int n = g3 * 16 + i;
            dsum = fmaf(m_l[n], Wmw[k * N_ + n], dsum);
        }
        dsum += __shfl_xor(dsum, 1, 64);
        dsum += __shfl_xor(dsum, 2, 64);
        dsum += __shfl_xor(dsum, 4, 64);
        if (g3 == 0) gw_l[k] = tanhf(dsum + Wmb[k]) * Whw[k];
    }
    __syncthreads();

    // W fragments (hi/lo bf16) + bias + per-lane gate weight
    short8 wh[4], wlo[4];
#pragma unroll
    for (int ks = 0; ks < 4; ++ks) {
        float4 wa  = Ww4[kk * 32 + ks * 8 + g * 2];
        float4 wb4 = Ww4[kk * 32 + ks * 8 + g * 2 + 1];
        split_bf16(wa, wb4, wh[ks], wlo[ks]);
    }
    const float wbr  = Wb[kk];
    const float gmwr = gw_l[kk];

    float4 cacc[8];
#pragma unroll
    for (int m = 0; m < 8; ++m) cacc[m] = make_float4(0.f, 0.f, 0.f, 0.f);
    float zacc = 0.f;

#pragma unroll
    for (int step = 0; step < 4; ++step) {
        float4 xq[8];
        LOADX(xq, step);
        // gate dots via 3-term bf16 MFMA (fp32-accurate)
        f32x4 acc = {0.f, 0.f, 0.f, 0.f};
#pragma unroll
        for (int ks = 0; ks < 4; ++ks) {
            short8 xh, xl;
            split_bf16(xq[2*ks], xq[2*ks+1], xh, xl);
            acc = __builtin_amdgcn_mfma_f32_16x16x32_bf16(xh, wh[ks],  acc, 0, 0, 0);
            acc = __builtin_amdgcn_mfma_f32_16x16x32_bf16(xl, wh[ks],  acc, 0, 0, 0);
            acc = __builtin_amdgcn_mfma_f32_16x16x32_bf16(xh, wlo[ks], acc, 0, 0, 0);
        }
        // per lane: D[t=g*4+i][k=kk] -> tanh -> *gmw -> sum over k (bits 0-3)
        float pl[4];
#pragma unroll
        for (int i = 0; i < 4; ++i)
            pl[i] = tanh_fast(acc[i] + wbr) * gmwr;
#pragma unroll
        for (int i = 0; i < 4; ++i) {
            pl[i] += __shfl_xor(pl[i], 1, 64);
            pl[i] += __shfl_xor(pl[i], 2, 64);
            pl[i] += __shfl_xor(pl[i], 4, 64);
            pl[i] += __shfl_xor(pl[i], 8, 64);
        }
        // unshifted exp (logits bounded by sum|gmw| <= 4)
        float e0 = exp2f(pl[0] * LOG2E), e1 = exp2f(pl[1] * LOG2E);
        float e2 = exp2f(pl[2] * LOG2E), e3 = exp2f(pl[3] * LOG2E);
        zacc += (e0 + e1) + (e2 + e3);
        // redistribute: lane's A-row t = kk -> take e_{kk&3} from g' = kk>>2
        int src = (kk >> 2) << 4;
        float s0 = __shfl(e0, src, 64), s1 = __shfl(e1, src, 64);
        float s2 = __shfl(e2, src, 64), s3 = __shfl(e3, src, 64);
        float E = (kk & 2) ? ((kk & 1) ? s3 : s2) : ((kk & 1) ? s1 : s0);
        // fp32 e-weighted accumulation
#pragma unroll
        for (int m = 0; m < 8; ++m) {
            cacc[m].x = fmaf(E, xq[m].x, cacc[m].x);
            cacc[m].y = fmaf(E, xq[m].y, cacc[m].y);
            cacc[m].z = fmaf(E, xq[m].z, cacc[m].z);
            cacc[m].w = fmaf(E, xq[m].w, cacc[m].w);
        }
    }
    // reduce cacc and z over kk (lane bits 0-3)
#pragma unroll
    for (int m = 0; m < 8; ++m) {
#pragma unroll
        for (int mask = 1; mask <= 8; mask <<= 1) {
            cacc[m].x += __shfl_xor(cacc[m].x, mask, 64);
            cacc[m].y += __shfl_xor(cacc[m].y, mask, 64);
            cacc[m].z += __shfl_xor(cacc[m].z, mask, 64);
            cacc[m].w += __shfl_xor(cacc[m].w, mask, 64);
        }
    }
    float z = zacc;
    z += __shfl_xor(z, 16, 64);
    z += __shfl_xor(z, 32, 64);
    if (kk == 0) {
#pragma unroll
        for (int m = 0; m < 8; ++m) {
            int nb = 32 * (m >> 1) + 8 * g + 4 * (m & 1);
            red[w * N_ + nb + 0] = cacc[m].x;
            red[w * N_ + nb + 1] = cacc[m].y;
            red[w * N_ + nb + 2] = cacc[m].z;
            red[w * N_ + nb + 3] = cacc[m].w;
        }
    }
    if (lane == 0) zred[w] = z;
    __syncthreads();
    if (tid < N_) {
        attp[(size_t)blk * APS + tid] =
            (red[tid] + red[N_ + tid]) + (red[2*N_ + tid] + red[3*N_ + tid]);
    } else if (tid == N_) {
        attp[(size_t)blk * APS + N_] =
            (zred[0] + zred[1]) + (zred[2] + zred[3]);
    }
}

// K3: merge TSPL split partials per (b,h): c = sum ci / sum Zi
__global__ __launch_bounds__(128) void k_red(const float* __restrict__ attp,
                                             float* __restrict__ out) {
    int bh = blockIdx.x, tid = threadIdx.x;
    float Z = 0.f, c = 0.f;
#pragma unroll
    for (int s = 0; s < TSPL; ++s) {
        const float* pp = &attp[(size_t)(bh * TSPL + s) * APS];
        Z += pp[N_];
        c += pp[tid];
    }
    out[bh * N_ + tid] = c / Z;
}

extern "C" void kernel_launch(void* const* d_in, const int* in_sizes, int n_in,
                              void* d_out, int out_size, void* d_ws, size_t ws_size,
                              hipStream_t stream) {
    const float* hyp = (const float*)d_in[0];
    const float* Ww  = (const float*)d_in[1];
    const float* Wb  = (const float*)d_in[2];
    const float* Wmw = (const float*)d_in[3];
    const float* Wmb = (const float*)d_in[4];
    const float* Whw = (const float*)d_in[5];
    // d_in[6] = Wh_b: unused (softmax shift-invariant)
    float* out  = (float*)d_out;
    float* part = (float*)d_ws;                  // 2048*128 f  = 1 MB
    float* attp = part + 2048 * N_;              // 2048*132 f ~= 1.06 MB

    k_mean<<<dim3(B_ * H_ * TSPL), 256, 0, stream>>>((const float4*)hyp,
                                                     (float4*)part);
    k_att <<<dim3(B_ * H_ * TSPL), 256, 0, stream>>>(hyp, Ww, Wb, part,
                                                     Wmw, Wmb, Whw, attp);
    k_red <<<dim3(B_ * H_), 128, 0, stream>>>(attp, out);
}

// Round 9
// 105.288 us; speedup vs baseline: 1.5491x; 1.5491x over previous
//
#include <hip/hip_runtime.h>
#include <hip/hip_fp16.h>
#include <math.h>

// Attention_57406532878693: T=2048,B=32,D=1024,H=8,N=128,N2=16
#define T_   2048
#define B_   32
#define D_   1024
#define H_   8
#define N_   128
#define NK   16          // N2 gate width
#define TSPL 8           // T-splits per (b,h)
#define TBLK (T_/TSPL)   // 256 t per unit
#define BD4  (B_*D_/4)
#define APS  132         // attp stride per unit (128 c + Z + pad)
#define LOG2E 1.4426950408889634f

typedef __attribute__((ext_vector_type(8))) short short8;   // bf16x8 frag
typedef __attribute__((ext_vector_type(4))) float f32x4;    // C/D frag

// split 8 fp32 (two float4) into truncated bf16 hi + bf16(lo) fragments
__device__ __forceinline__ void split_bf16(float4 a, float4 b,
                                           short8& hi, short8& lo) {
    union { uint32_t u[4]; short8 v; } H, L;
    uint32_t x0 = __float_as_uint(a.x), x1 = __float_as_uint(a.y);
    uint32_t x2 = __float_as_uint(a.z), x3 = __float_as_uint(a.w);
    uint32_t x4 = __float_as_uint(b.x), x5 = __float_as_uint(b.y);
    uint32_t x6 = __float_as_uint(b.z), x7 = __float_as_uint(b.w);
    H.u[0] = (x0 >> 16) | (x1 & 0xFFFF0000u);
    H.u[1] = (x2 >> 16) | (x3 & 0xFFFF0000u);
    H.u[2] = (x4 >> 16) | (x5 & 0xFFFF0000u);
    H.u[3] = (x6 >> 16) | (x7 & 0xFFFF0000u);
    float l0 = a.x - __uint_as_float(x0 & 0xFFFF0000u);
    float l1 = a.y - __uint_as_float(x1 & 0xFFFF0000u);
    float l2 = a.z - __uint_as_float(x2 & 0xFFFF0000u);
    float l3 = a.w - __uint_as_float(x3 & 0xFFFF0000u);
    float l4 = b.x - __uint_as_float(x4 & 0xFFFF0000u);
    float l5 = b.y - __uint_as_float(x5 & 0xFFFF0000u);
    float l6 = b.z - __uint_as_float(x6 & 0xFFFF0000u);
    float l7 = b.w - __uint_as_float(x7 & 0xFFFF0000u);
    L.u[0] = (__float_as_uint(l0) >> 16) | (__float_as_uint(l1) & 0xFFFF0000u);
    L.u[1] = (__float_as_uint(l2) >> 16) | (__float_as_uint(l3) & 0xFFFF0000u);
    L.u[2] = (__float_as_uint(l4) >> 16) | (__float_as_uint(l5) & 0xFFFF0000u);
    L.u[3] = (__float_as_uint(l6) >> 16) | (__float_as_uint(l7) & 0xFFFF0000u);
    hi = H.v; lo = L.v;
}

__device__ __forceinline__ float tanh_fast(float d) {
    return 1.f - 2.f * __frcp_rn(exp2f(d * (2.f * LOG2E)) + 1.f);
}

// load 8 float4 of x for one 16-t step (lane's t-row = t0+step*64+w*16+kk)
#define LOADX(dst, step_) { \
    const int trow_ = t0 + (step_) * 64 + w * 16 + kk; \
    const size_t rb_ = (size_t)trow_ * BD4 + base4; \
    (dst)[0] = hyp4[rb_ + g * 2];      (dst)[1] = hyp4[rb_ + g * 2 + 1]; \
    (dst)[2] = hyp4[rb_ + 8 + g * 2];  (dst)[3] = hyp4[rb_ + 8 + g * 2 + 1]; \
    (dst)[4] = hyp4[rb_ + 16 + g * 2]; (dst)[5] = hyp4[rb_ + 16 + g * 2 + 1]; \
    (dst)[6] = hyp4[rb_ + 24 + g * 2]; (dst)[7] = hyp4[rb_ + 24 + g * 2 + 1]; }

// K1: one block per (bh,spl). One x read: colsums -> part[blk][128],
// P[t][k] = tanh(x.Ww + b) staged in LDS, flushed coalesced to Pbuf (fp16).
__global__ __launch_bounds__(256, 4) void k_p(const float* __restrict__ hyp,
                                              const float* __restrict__ Ww,
                                              const float* __restrict__ Wb,
                                              float* __restrict__ part,
                                              __half* __restrict__ Pbuf) {
    __shared__ float red[4 * N_];
    __shared__ __half Pl[TBLK * NK];     // 8 KB unit P staging
    const int tid  = threadIdx.x;
    const int lane = tid & 63;
    const int w    = tid >> 6;
    const int blk  = blockIdx.x;
    const int bh   = blk >> 3;
    const int spl  = blk & 7;
    const int b = bh >> 3, h = bh & 7;
    const int t0 = spl * TBLK;
    const float4* hyp4 = (const float4*)hyp;
    const float4* Ww4  = (const float4*)Ww;
    const int base4 = b * (D_ / 4) + h * (N_ / 4);
    const int kk = lane & 15;
    const int g  = lane >> 4;

    short8 wh[4], wlo[4];
#pragma unroll
    for (int ks = 0; ks < 4; ++ks) {
        float4 wa  = Ww4[kk * 32 + ks * 8 + g * 2];
        float4 wb4 = Ww4[kk * 32 + ks * 8 + g * 2 + 1];
        split_bf16(wa, wb4, wh[ks], wlo[ks]);
    }
    const float wbr = Wb[kk];

    float4 cs[8];
#pragma unroll
    for (int m = 0; m < 8; ++m) cs[m] = make_float4(0.f, 0.f, 0.f, 0.f);

#pragma unroll
    for (int step = 0; step < 4; ++step) {
        float4 xq[8];
        LOADX(xq, step);
#pragma unroll
        for (int m = 0; m < 8; ++m) {
            cs[m].x += xq[m].x; cs[m].y += xq[m].y;
            cs[m].z += xq[m].z; cs[m].w += xq[m].w;
        }
        f32x4 acc = {0.f, 0.f, 0.f, 0.f};
#pragma unroll
        for (int ks = 0; ks < 4; ++ks) {
            short8 xh, xl;
            split_bf16(xq[2*ks], xq[2*ks+1], xh, xl);
            acc = __builtin_amdgcn_mfma_f32_16x16x32_bf16(xh, wh[ks],  acc, 0, 0, 0);
            acc = __builtin_amdgcn_mfma_f32_16x16x32_bf16(xl, wh[ks],  acc, 0, 0, 0);
            acc = __builtin_amdgcn_mfma_f32_16x16x32_bf16(xh, wlo[ks], acc, 0, 0, 0);
        }
        // stage P[t_local = step*64+w*16+g*4+i][kk] in LDS
        const int tl = step * 64 + w * 16 + g * 4;
#pragma unroll
        for (int i = 0; i < 4; ++i)
            Pl[(tl + i) * NK + kk] = __float2half(tanh_fast(acc[i] + wbr));
    }
    __syncthreads();
    // coalesced flush: 8 KB contiguous (unit is t-major inside bh)
    {
        const uint4* src = (const uint4*)Pl;
        uint4* dst = (uint4*)(Pbuf + ((size_t)bh * T_ + t0) * NK);
        dst[tid]       = src[tid];
        dst[tid + 256] = src[tid + 256];
    }
    // reduce colsums over kk (lane bits 0-3)
#pragma unroll
    for (int m = 0; m < 8; ++m) {
#pragma unroll
        for (int mask = 1; mask <= 8; mask <<= 1) {
            cs[m].x += __shfl_xor(cs[m].x, mask, 64);
            cs[m].y += __shfl_xor(cs[m].y, mask, 64);
            cs[m].z += __shfl_xor(cs[m].z, mask, 64);
            cs[m].w += __shfl_xor(cs[m].w, mask, 64);
        }
    }
    if (kk == 0) {
#pragma unroll
        for (int m = 0; m < 8; ++m) {
            int nb = 32 * (m >> 1) + 8 * g + 4 * (m & 1);
            red[w * N_ + nb + 0] = cs[m].x;
            red[w * N_ + nb + 1] = cs[m].y;
            red[w * N_ + nb + 2] = cs[m].z;
            red[w * N_ + nb + 3] = cs[m].w;
        }
    }
    __syncthreads();
    if (tid < N_)
        part[blk * N_ + tid] = (red[tid] + red[N_ + tid])
                             + (red[2*N_ + tid] + red[3*N_ + tid]);
}

// K3: one block per (bh,spl). XCD-matched reverse order: unit keeps its
// u%8 XCD (matches k_p's residency) and descends temporally per XCD.
// Prologue: mean from part + gm. Hot loop: logit from own fp16 P row
// (16 fma), unshifted exp (|l|<=4), weighted accumulate.
__global__ __launch_bounds__(256, 4) void k_att(const float* __restrict__ hyp,
                                                const float* __restrict__ part,
                                                const float* __restrict__ Wmw,
                                                const float* __restrict__ Wmb,
                                                const float* __restrict__ Whw,
                                                const __half* __restrict__ Pbuf,
                                                float* __restrict__ attp) {
    __shared__ float red[4 * N_];
    __shared__ float zred[4];
    __shared__ float m_l[N_];
    __shared__ float gw_l[NK];
    const int tid  = threadIdx.x;
    const int lane = tid & 63;
    const int w    = tid >> 6;
    const int j    = (int)blockIdx.x;
    const int blk  = (j & 7) + 8 * (255 - (j >> 3));   // XCD-matched reverse
    const int bh   = blk >> 3;
    const int spl  = blk & 7;
    const int b = bh >> 3, h = bh & 7;
    const int t0 = spl * TBLK;
    const float4* hyp4 = (const float4*)hyp;
    const int base4 = b * (D_ / 4) + h * (N_ / 4);
    const int kk = lane & 15;
    const int g  = lane >> 4;

    // mean for this bh
    if (tid < N_) {
        float s = 0.f;
#pragma unroll
        for (int s8 = 0; s8 < TSPL; ++s8) s += part[(bh * TSPL + s8) * N_ + tid];
        m_l[tid] = s * (1.f / (float)T_);
    }
    __syncthreads();
    // gm: gw_l[k] = tanh(m.Wmw_k + Wmb_k) * Whw_k
    if (tid < N_) {
        int k = tid >> 3, g3 = tid & 7;
        float dsum = 0.f;
#pragma unroll
        for (int i = 0; i < 16; ++i) {
            int n = g3 * 16 + i;
            dsum = fmaf(m_l[n], Wmw[k * N_ + n], dsum);
        }
        dsum += __shfl_xor(dsum, 1, 64);
        dsum += __shfl_xor(dsum, 2, 64);
        dsum += __shfl_xor(dsum, 4, 64);
        if (g3 == 0) gw_l[k] = tanhf(dsum + Wmb[k]) * Whw[k];
    }
    __syncthreads();
    float gmv[NK];
#pragma unroll
    for (int jq = 0; jq < NK; ++jq) gmv[jq] = gw_l[jq];

    float4 cacc[8];
#pragma unroll
    for (int m = 0; m < 8; ++m) cacc[m] = make_float4(0.f, 0.f, 0.f, 0.f);
    float zacc = 0.f;

#pragma unroll
    for (int step = 0; step < 4; ++step) {
        const int tr = t0 + step * 64 + w * 16 + kk;
        // own P row: 16 fp16 = 32 B = 2 uint4
        union { uint4 u; __half2 h[8]; } P0, P1;
        const uint4* pv = (const uint4*)(Pbuf + (size_t)(bh * T_ + tr) * NK);
        P0.u = pv[0]; P1.u = pv[1];
        float4 xq[8];
        LOADX(xq, step);
        float lg = 0.f;
#pragma unroll
        for (int q = 0; q < 4; ++q) {
            float2 f0 = __half22float2(P0.h[q]);
            float2 f1 = __half22float2(P1.h[q]);
            lg = fmaf(f0.x, gmv[2*q + 0], lg);
            lg = fmaf(f0.y, gmv[2*q + 1], lg);
            lg = fmaf(f1.x, gmv[8 + 2*q + 0], lg);
            lg = fmaf(f1.y, gmv[8 + 2*q + 1], lg);
        }
        float e = exp2f(lg * LOG2E);     // unshifted: |lg| <= sum|Whw| <= 4
        zacc += e;
#pragma unroll
        for (int m = 0; m < 8; ++m) {
            cacc[m].x = fmaf(e, xq[m].x, cacc[m].x);
            cacc[m].y = fmaf(e, xq[m].y, cacc[m].y);
            cacc[m].z = fmaf(e, xq[m].z, cacc[m].z);
            cacc[m].w = fmaf(e, xq[m].w, cacc[m].w);
        }
    }
    // reduce cacc and z over kk (lane bits 0-3)
#pragma unroll
    for (int m = 0; m < 8; ++m) {
#pragma unroll
        for (int mask = 1; mask <= 8; mask <<= 1) {
            cacc[m].x += __shfl_xor(cacc[m].x, mask, 64);
            cacc[m].y += __shfl_xor(cacc[m].y, mask, 64);
            cacc[m].z += __shfl_xor(cacc[m].z, mask, 64);
            cacc[m].w += __shfl_xor(cacc[m].w, mask, 64);
        }
    }
    float z = zacc;
    z += __shfl_xor(z, 1, 64);
    z += __shfl_xor(z, 2, 64);
    z += __shfl_xor(z, 4, 64);
    z += __shfl_xor(z, 8, 64);
    if (kk == 0) {
#pragma unroll
        for (int m = 0; m < 8; ++m) {
            int nb = 32 * (m >> 1) + 8 * g + 4 * (m & 1);
            red[w * N_ + nb + 0] = cacc[m].x;
            red[w * N_ + nb + 1] = cacc[m].y;
            red[w * N_ + nb + 2] = cacc[m].z;
            red[w * N_ + nb + 3] = cacc[m].w;
        }
    }
    if (lane == 0) zred[w] = z;
    __syncthreads();
    if (tid < N_) {
        attp[(size_t)blk * APS + tid] =
            (red[tid] + red[N_ + tid]) + (red[2*N_ + tid] + red[3*N_ + tid]);
    } else if (tid == N_) {
        attp[(size_t)blk * APS + N_] =
            (zred[0] + zred[1]) + (zred[2] + zred[3]);
    }
}

// K4: merge TSPL split partials per (b,h): c = sum ci / sum Zi
__global__ __launch_bounds__(128) void k_red(const float* __restrict__ attp,
                                             float* __restrict__ out) {
    int bh = blockIdx.x, tid = threadIdx.x;
    float Z = 0.f, c = 0.f;
#pragma unroll
    for (int s = 0; s < TSPL; ++s) {
        const float* pp = &attp[(size_t)(bh * TSPL + s) * APS];
        Z += pp[N_];
        c += pp[tid];
    }
    out[bh * N_ + tid] = c / Z;
}

extern "C" void kernel_launch(void* const* d_in, const int* in_sizes, int n_in,
                              void* d_out, int out_size, void* d_ws, size_t ws_size,
                              hipStream_t stream) {
    const float* hyp = (const float*)d_in[0];
    const float* Ww  = (const float*)d_in[1];
    const float* Wb  = (const float*)d_in[2];
    const float* Wmw = (const float*)d_in[3];
    const float* Wmb = (const float*)d_in[4];
    const float* Whw = (const float*)d_in[5];
    // d_in[6] = Wh_b: unused (softmax shift-invariant)
    float* out  = (float*)d_out;
    float* part = (float*)d_ws;                  // 2048*128 f  = 1 MB
    float* attp = part + 2048 * N_;              // 2048*132 f ~= 1.06 MB
    __half* Pbuf = (__half*)((char*)d_ws + (4 << 20));  // 16 MB fp16 P

    k_p  <<<dim3(B_ * H_ * TSPL), 256, 0, stream>>>(hyp, Ww, Wb, part, Pbuf);
    k_att<<<dim3(B_ * H_ * TSPL), 256, 0, stream>>>(hyp, part, Wmw, Wmb, Whw,
                                                    Pbuf, attp);
    k_red<<<dim3(B_ * H_), 128, 0, stream>>>(attp, out);
}